// Round 1
// baseline (450.610 us; speedup 1.0000x reference)
//
#include <hip/hip_runtime.h>

#define L_SEQ 100
#define E_DIM 100
#define H_DIM 64
#define G_DIM 192   // 3*H
#define ROWS  16    // rows per block
#define SP    194   // padded inner stride for S (2-way bank = free)
#define HP    68    // padded inner stride for h (2-way bank = free)

typedef __attribute__((ext_vector_type(8))) short bf16x8;
typedef __attribute__((ext_vector_type(4))) float f32x4;
typedef __attribute__((ext_vector_type(4))) float float4v;

static __device__ __forceinline__ unsigned short f2bf(float f) {
    union { float f; unsigned u; } v; v.f = f;
    unsigned r = v.u + 0x7FFFu + ((v.u >> 16) & 1u);  // RNE
    return (unsigned short)(r >> 16);
}
static __device__ __forceinline__ float sigmoidf_(float x) {
    return 1.f / (1.f + __expf(-x));
}
static __device__ __forceinline__ float tanhf_(float x) {
    return 1.f - 2.f / (__expf(2.f * x) + 1.f);
}

__global__ __launch_bounds__(512, 2) void gru_model_kernel(
    const float* __restrict__ x,   const float* __restrict__ Win,
    const float* __restrict__ bin, const float* __restrict__ Wh,
    const float* __restrict__ bh,  const float* __restrict__ Wfc,
    const float* __restrict__ bfc, float* __restrict__ out)
{
    __shared__ float S_ti[2][ROWS][SP];
    __shared__ float S_th[2][ROWS][SP];
    __shared__ float h_st[ROWS][HP];
    __shared__ float bin_l[G_DIM], bh_l[G_DIM];

    const int tid  = threadIdx.x;
    const int w    = tid >> 6, l = tid & 63;
    const int ns   = w & 3,  kh = w >> 2;     // N-slice, K-half owned by this wave
    const int c16  = l & 15, g  = l >> 4;
    const int row0 = blockIdx.x * ROWS;
    const int colg = ns * 48 + c16;

    if (tid < G_DIM) { bin_l[tid] = bin[tid]; bh_l[tid] = bh[tid]; }
    for (int i = tid; i < ROWS * HP; i += 512) (&h_st[0][0])[i] = 0.f;

    // ---- B-operand weight fragments, resident in registers ----
    // B layout: lane l holds B[ktile*32 + (l>>4)*8 + j][ntile*16 + (l&15)]
    bf16x8 bwin[2][3];
    bf16x8 bwh[3];
    #pragma unroll
    for (int kt = 0; kt < 2; ++kt)
      #pragma unroll
      for (int nt = 0; nt < 3; ++nt) {
        #pragma unroll
        for (int j = 0; j < 8; ++j) {
            int k = (kh * 2 + kt) * 32 + g * 8 + j;
            float v = (k < E_DIM) ? Win[k * G_DIM + colg + nt * 16] : 0.f;
            bwin[kt][nt][j] = (short)f2bf(v);
        }
      }
    #pragma unroll
    for (int nt = 0; nt < 3; ++nt)
      #pragma unroll
      for (int j = 0; j < 8; ++j) {
          int k = kh * 32 + g * 8 + j;
          bwh[nt][j] = (short)f2bf(Wh[k * G_DIM + colg + nt * 16]);
      }

    const float* xlane = x + (size_t)(row0 + c16) * (L_SEQ * E_DIM);
    const int r = tid >> 5, q = tid & 31;   // gate-phase mapping: 32 threads per row

    __syncthreads();

    for (int phase = 0; phase < 2; ++phase) {
      for (int t = 0; t < L_SEQ; ++t) {
        // ---------- GEMM phase ----------
        // A_h fragment: A[l&15][8*(l>>4)+j] from fp32 h in LDS
        bf16x8 ah;
        {
            const float* hp = &h_st[c16][kh * 32 + g * 8];
            float hv[8];
            *(float4v*)&hv[0] = *(const float4v*)&hp[0];
            *(float4v*)&hv[4] = *(const float4v*)&hp[4];
            #pragma unroll
            for (int j = 0; j < 8; ++j) ah[j] = (short)f2bf(hv[j]);
        }
        // A_x fragments (k >= 100 zero-padded)
        bf16x8 ax[2];
        const float* xp = xlane + t * E_DIM;
        #pragma unroll
        for (int kt = 0; kt < 2; ++kt) {
            int k0 = (kh * 2 + kt) * 32 + g * 8;
            float xv[8];
            if (k0 + 7 < E_DIM) {
                *(float4v*)&xv[0] = *(const float4v*)&xp[k0];
                *(float4v*)&xv[4] = *(const float4v*)&xp[k0 + 4];
            } else {
                #pragma unroll
                for (int j = 0; j < 8; ++j) {
                    int k = k0 + j;
                    xv[j] = (k < E_DIM) ? xp[k] : 0.f;
                }
            }
            #pragma unroll
            for (int j = 0; j < 8; ++j) ax[kt][j] = (short)f2bf(xv[j]);
        }
        const f32x4 zero = {0.f, 0.f, 0.f, 0.f};
        #pragma unroll
        for (int nt = 0; nt < 3; ++nt) {
            f32x4 ai = __builtin_amdgcn_mfma_f32_16x16x32_bf16(ax[0], bwin[0][nt], zero, 0, 0, 0);
            ai       = __builtin_amdgcn_mfma_f32_16x16x32_bf16(ax[1], bwin[1][nt], ai,   0, 0, 0);
            f32x4 ahh= __builtin_amdgcn_mfma_f32_16x16x32_bf16(ah,    bwh[nt],     zero, 0, 0, 0);
            // C/D layout: col = lane&15 (within n-tile), row = (lane>>4)*4 + reg
            #pragma unroll
            for (int rr = 0; rr < 4; ++rr) {
                S_ti[kh][g * 4 + rr][colg + nt * 16] = ai[rr];
                S_th[kh][g * 4 + rr][colg + nt * 16] = ahh[rr];
            }
        }
        __syncthreads();
        // ---------- gate phase: 32 threads per row ----------
        float vti[6], vth[6];
        float sti = 0.f, ssti = 0.f, sth = 0.f, ssth = 0.f;
        #pragma unroll
        for (int i = 0; i < 6; ++i) {
            int c = q + 32 * i;
            float a = S_ti[0][r][c] + S_ti[1][r][c] + bin_l[c];
            float b = S_th[0][r][c] + S_th[1][r][c] + bh_l[c];
            vti[i] = a; vth[i] = b;
            sti += a; ssti += a * a; sth += b; ssth += b * b;
        }
        float mti = 0.f, rti = 1.f, mth = 0.f, rth = 1.f;
        if (phase) {  // loop 2: standardize ti and th separately, ddof=1
            #pragma unroll
            for (int m = 1; m < 32; m <<= 1) {
                sti  += __shfl_xor(sti, m);
                ssti += __shfl_xor(ssti, m);
                sth  += __shfl_xor(sth, m);
                ssth += __shfl_xor(ssth, m);
            }
            mti = sti * (1.f / G_DIM);
            rti = rsqrtf(fmaxf((ssti - (float)G_DIM * mti * mti) * (1.f / (G_DIM - 1)), 1e-24f));
            mth = sth * (1.f / G_DIM);
            rth = rsqrtf(fmaxf((ssth - (float)G_DIM * mth * mth) * (1.f / (G_DIM - 1)), 1e-24f));
        }
        #pragma unroll
        for (int half = 0; half < 2; ++half) {
            int c = q + 32 * half;
            float tir  = (vti[half + 0] - mti) * rti;   // cols: c
            float tiz  = (vti[half + 2] - mti) * rti;   //       c + 64
            float tin  = (vti[half + 4] - mti) * rti;   //       c + 128
            float thr2 = (vth[half + 0] - mth) * rth;
            float thz  = (vth[half + 2] - mth) * rth;
            float thn  = (vth[half + 4] - mth) * rth;
            float rt  = sigmoidf_(tir + thr2);
            float zt  = sigmoidf_(tiz + thz);
            float nt2 = tanhf_(tin + rt * thn);
            float hv  = h_st[r][c];
            h_st[r][c] = (1.f - zt) * nt2 + zt * hv;
        }
        __syncthreads();
      }
    }

    // ---------- epilogue: out = h @ W_fc + b_fc ----------
    float h0 = h_st[r][q], h1 = h_st[r][q + 32];
    float p0 = h0 * Wfc[2 * q]     + h1 * Wfc[2 * q + 64];
    float p1 = h0 * Wfc[2 * q + 1] + h1 * Wfc[2 * q + 65];
    #pragma unroll
    for (int m = 1; m < 32; m <<= 1) {
        p0 += __shfl_xor(p0, m);
        p1 += __shfl_xor(p1, m);
    }
    if (q == 0) {
        out[(row0 + r) * 2 + 0] = p0 + bfc[0];
        out[(row0 + r) * 2 + 1] = p1 + bfc[1];
    }
}

extern "C" void kernel_launch(void* const* d_in, const int* in_sizes, int n_in,
                              void* d_out, int out_size, void* d_ws, size_t ws_size,
                              hipStream_t stream) {
    const float* x   = (const float*)d_in[0];
    const float* Win = (const float*)d_in[1];
    const float* bin = (const float*)d_in[2];
    const float* Wh  = (const float*)d_in[3];
    const float* bh  = (const float*)d_in[4];
    const float* Wfc = (const float*)d_in[5];
    const float* bfc = (const float*)d_in[6];
    float* out = (float*)d_out;
    gru_model_kernel<<<dim3(4096 / ROWS), dim3(512), 0, stream>>>(
        x, Win, bin, Wh, bh, Wfc, bfc, out);
}

// Round 2
// 385.750 us; speedup vs baseline: 1.1681x; 1.1681x over previous
//
#include <hip/hip_runtime.h>

#define L_SEQ 100
#define E_DIM 100
#define H_DIM 64
#define G_DIM 192   // 3*H
#define B_TOT 4096
#define ROWS  8     // batch rows per recurrent block
#define SP    194   // fp32 scratch stride (2-way banks = free)
#define HBP   72    // h_bf stride in bf16 (144 B rows -> 2-way = free)

typedef __attribute__((ext_vector_type(8))) short bf16x8;
typedef __attribute__((ext_vector_type(4))) float f32x4;
typedef __attribute__((ext_vector_type(4))) float float4v;

static __device__ __forceinline__ unsigned short f2bf(float f) {
    union { float f; unsigned u; } v; v.f = f;
    unsigned r = v.u + 0x7FFFu + ((v.u >> 16) & 1u);  // RNE
    return (unsigned short)(r >> 16);
}
static __device__ __forceinline__ float bf2f(unsigned short u) {
    union { unsigned u; float f; } v; v.u = ((unsigned)u) << 16;
    return v.f;
}
static __device__ __forceinline__ float sigmoidf_(float x) { return 1.f / (1.f + __expf(-x)); }
static __device__ __forceinline__ float tanhf_(float x)    { return 1.f - 2.f / (__expf(2.f * x) + 1.f); }

// ---------------- pre-pass: ti = bf16( x @ W_in )  (no bias) ----------------
// grid: m_rows/16 blocks of 256 (4 waves, one 48-col n-slice each)
__global__ __launch_bounds__(256, 4) void ti_proj_kernel(
    const float* __restrict__ x, const float* __restrict__ Win,
    unsigned short* __restrict__ tiw)
{
    __shared__ unsigned short T[16][200];   // 400 B rows

    const int tid = threadIdx.x;
    const int w   = tid >> 6, l = tid & 63;
    const int c16 = l & 15,  g = l >> 4;
    const int m0  = blockIdx.x * 16;
    const int colg = w * 48 + c16;

    // B frags: Win[32kt+8g+j][colg+16nt], zero-padded past k=100
    bf16x8 bw[4][3];
    #pragma unroll
    for (int kt = 0; kt < 4; ++kt)
      #pragma unroll
      for (int nt = 0; nt < 3; ++nt)
        #pragma unroll
        for (int j = 0; j < 8; ++j) {
            int k = 32 * kt + 8 * g + j;
            float v = (k < E_DIM) ? Win[k * G_DIM + colg + 16 * nt] : 0.f;
            bw[kt][nt][j] = (short)f2bf(v);
        }

    // A frags from x row m0+c16
    const float* xr = x + (size_t)(m0 + c16) * E_DIM;
    bf16x8 ax[4];
    #pragma unroll
    for (int kt = 0; kt < 4; ++kt) {
        int k0 = 32 * kt + 8 * g;
        float xv[8];
        if (k0 + 7 < E_DIM) {
            *(float4v*)&xv[0] = *(const float4v*)&xr[k0];
            *(float4v*)&xv[4] = *(const float4v*)&xr[k0 + 4];
        } else {
            #pragma unroll
            for (int j = 0; j < 8; ++j) {
                int k = k0 + j;
                xv[j] = (k < E_DIM) ? xr[k] : 0.f;
            }
        }
        #pragma unroll
        for (int j = 0; j < 8; ++j) ax[kt][j] = (short)f2bf(xv[j]);
    }

    const f32x4 zero = {0.f, 0.f, 0.f, 0.f};
    f32x4 acc[3] = {zero, zero, zero};
    #pragma unroll
    for (int nt = 0; nt < 3; ++nt)
      #pragma unroll
      for (int kt = 0; kt < 4; ++kt)
        acc[nt] = __builtin_amdgcn_mfma_f32_16x16x32_bf16(ax[kt], bw[kt][nt], acc[nt], 0, 0, 0);

    #pragma unroll
    for (int nt = 0; nt < 3; ++nt)
      #pragma unroll
      for (int rr = 0; rr < 4; ++rr)
        T[4 * g + rr][colg + 16 * nt] = f2bf(acc[nt][rr]);
    __syncthreads();

    // coalesced 16B stores: 384 chunks (16 rows x 24)
    {
        int c = tid, row = c / 24, j = c - row * 24;
        *(float4v*)(tiw + (size_t)(m0 + row) * G_DIM + j * 8) =
            *(const float4v*)((const char*)&T[0][0] + row * 400 + j * 16);
        if (tid < 128) {
            int c2 = tid + 256, row2 = c2 / 24, j2 = c2 - row2 * 24;
            *(float4v*)(tiw + (size_t)(m0 + row2) * G_DIM + j2 * 8) =
                *(const float4v*)((const char*)&T[0][0] + row2 * 400 + j2 * 16);
        }
    }
}

// ---------------- recurrent kernel ----------------
// MODE 0: ti from tiw (pre-pass).  MODE 1: ti computed inline from x.
template<int MODE>
__global__ __launch_bounds__(256, 2) void gru_rec_kernel(
    const float* __restrict__ x, const unsigned short* __restrict__ tiw,
    const float* __restrict__ Win, const float* __restrict__ bin,
    const float* __restrict__ Wh,  const float* __restrict__ bh,
    const float* __restrict__ Wfc, const float* __restrict__ bfc,
    float* __restrict__ out, int row_off)
{
    __shared__ float S_ti[16][SP];
    __shared__ float S_th[16][SP];
    __shared__ unsigned short h_bf[16][HBP];
    __shared__ float bin_l[G_DIM], bh_l[G_DIM];

    const int tid = threadIdx.x;
    const int w   = tid >> 6, l = tid & 63;
    const int c16 = l & 15,  g = l >> 4;
    const int colg = w * 48 + c16;
    const int row0 = blockIdx.x * ROWS;          // chunk-local
    const int r = tid >> 5, q = tid & 31;        // gate mapping

    if (tid < G_DIM) { bin_l[tid] = bin[tid]; bh_l[tid] = bh[tid]; }
    for (int i = tid; i < 16 * HBP; i += 256) (&h_bf[0][0])[i] = 0;

    // W_h fragments (K=64)
    bf16x8 bwh[2][3];
    #pragma unroll
    for (int kt = 0; kt < 2; ++kt)
      #pragma unroll
      for (int nt = 0; nt < 3; ++nt)
        #pragma unroll
        for (int j = 0; j < 8; ++j) {
            int k = 32 * kt + 8 * g + j;
            bwh[kt][nt][j] = (short)f2bf(Wh[k * G_DIM + colg + 16 * nt]);
        }

    bf16x8 bwin[4][3];
    const float* xlane = nullptr;
    if constexpr (MODE == 1) {
        #pragma unroll
        for (int kt = 0; kt < 4; ++kt)
          #pragma unroll
          for (int nt = 0; nt < 3; ++nt)
            #pragma unroll
            for (int j = 0; j < 8; ++j) {
                int k = 32 * kt + 8 * g + j;
                float v = (k < E_DIM) ? Win[k * G_DIM + colg + 16 * nt] : 0.f;
                bwin[kt][nt][j] = (short)f2bf(v);
            }
        int xr = row_off + row0 + c16;
        if (xr > B_TOT - 1) xr = B_TOT - 1;     // clamp padding rows
        xlane = x + (size_t)xr * (L_SEQ * E_DIM);
    }

    const unsigned short* tibase = nullptr;
    if constexpr (MODE == 0)
        tibase = tiw + (size_t)(row0 + r) * L_SEQ * G_DIM + q;

    float hq0 = 0.f, hq1 = 0.f;   // fp32 master h for cols q, q+32 of row r
    __syncthreads();

    for (int s = 0; s < 2 * L_SEQ; ++s) {
        const int t = (s < L_SEQ) ? s : s - L_SEQ;
        const int phase = (s >= L_SEQ);

        // ---------- GEMM phase ----------
        unsigned short tiC[6];
        if constexpr (MODE == 0) {
            const unsigned short* tp = tibase + (size_t)t * G_DIM;
            #pragma unroll
            for (int i = 0; i < 6; ++i) tiC[i] = tp[32 * i];   // issued early, drained at barrier
        }

        bf16x8 ah0 = *(const bf16x8*)&h_bf[c16][8 * g];
        bf16x8 ah1 = *(const bf16x8*)&h_bf[c16][32 + 8 * g];

        const f32x4 zero = {0.f, 0.f, 0.f, 0.f};
        f32x4 acch[3], acci[3];
        #pragma unroll
        for (int nt = 0; nt < 3; ++nt) {
            acch[nt] = __builtin_amdgcn_mfma_f32_16x16x32_bf16(ah0, bwh[0][nt], zero,     0, 0, 0);
            acch[nt] = __builtin_amdgcn_mfma_f32_16x16x32_bf16(ah1, bwh[1][nt], acch[nt], 0, 0, 0);
        }
        if constexpr (MODE == 1) {
            bf16x8 ax[4];
            const float* xp = xlane + t * E_DIM;
            #pragma unroll
            for (int kt = 0; kt < 4; ++kt) {
                int k0 = 32 * kt + 8 * g;
                float xv[8];
                if (k0 + 7 < E_DIM) {
                    *(float4v*)&xv[0] = *(const float4v*)&xp[k0];
                    *(float4v*)&xv[4] = *(const float4v*)&xp[k0 + 4];
                } else {
                    #pragma unroll
                    for (int j = 0; j < 8; ++j) { int k = k0 + j; xv[j] = (k < E_DIM) ? xp[k] : 0.f; }
                }
                #pragma unroll
                for (int j = 0; j < 8; ++j) ax[kt][j] = (short)f2bf(xv[j]);
            }
            #pragma unroll
            for (int nt = 0; nt < 3; ++nt) {
                acci[nt] = zero;
                #pragma unroll
                for (int kt = 0; kt < 4; ++kt)
                    acci[nt] = __builtin_amdgcn_mfma_f32_16x16x32_bf16(ax[kt], bwin[kt][nt], acci[nt], 0, 0, 0);
            }
        }
        #pragma unroll
        for (int nt = 0; nt < 3; ++nt)
          #pragma unroll
          for (int rr = 0; rr < 4; ++rr) {
              S_th[4 * g + rr][colg + 16 * nt] = acch[nt][rr];
              if constexpr (MODE == 1) S_ti[4 * g + rr][colg + 16 * nt] = acci[nt][rr];
          }
        __syncthreads();

        // ---------- gate phase: 32 threads per row ----------
        float vti[6], vth[6];
        float sti = 0.f, ssti = 0.f, sth = 0.f, ssth = 0.f;
        #pragma unroll
        for (int i = 0; i < 6; ++i) {
            int c = q + 32 * i;
            float a = ((MODE == 0) ? bf2f(tiC[i]) : S_ti[r][c]) + bin_l[c];
            float b = S_th[r][c] + bh_l[c];
            vti[i] = a; vth[i] = b;
            sti += a; ssti += a * a; sth += b; ssth += b * b;
        }
        float mti = 0.f, rti = 1.f, mth = 0.f, rth = 1.f;
        if (phase) {
            #pragma unroll
            for (int m = 1; m < 32; m <<= 1) {
                sti += __shfl_xor(sti, m); ssti += __shfl_xor(ssti, m);
                sth += __shfl_xor(sth, m); ssth += __shfl_xor(ssth, m);
            }
            mti = sti * (1.f / G_DIM);
            rti = rsqrtf(fmaxf((ssti - (float)G_DIM * mti * mti) * (1.f / (G_DIM - 1)), 1e-24f));
            mth = sth * (1.f / G_DIM);
            rth = rsqrtf(fmaxf((ssth - (float)G_DIM * mth * mth) * (1.f / (G_DIM - 1)), 1e-24f));
        }
        #pragma unroll
        for (int half = 0; half < 2; ++half) {
            float tir = (vti[half + 0] - mti) * rti;
            float tiz = (vti[half + 2] - mti) * rti;
            float tin = (vti[half + 4] - mti) * rti;
            float thr2 = (vth[half + 0] - mth) * rth;
            float thz  = (vth[half + 2] - mth) * rth;
            float thn  = (vth[half + 4] - mth) * rth;
            float rt  = sigmoidf_(tir + thr2);
            float zt  = sigmoidf_(tiz + thz);
            float nt2 = tanhf_(tin + rt * thn);
            float hv  = half ? hq1 : hq0;
            float hn  = (1.f - zt) * nt2 + zt * hv;
            if (half) hq1 = hn; else hq0 = hn;
            h_bf[r][q + 32 * half] = f2bf(hn);
        }
        __syncthreads();
    }

    // ---------- epilogue: out = h @ W_fc + b_fc ----------
    float p0 = hq0 * Wfc[2 * q]     + hq1 * Wfc[2 * (q + 32)];
    float p1 = hq0 * Wfc[2 * q + 1] + hq1 * Wfc[2 * (q + 32) + 1];
    #pragma unroll
    for (int m = 1; m < 32; m <<= 1) {
        p0 += __shfl_xor(p0, m);
        p1 += __shfl_xor(p1, m);
    }
    if (q == 0) {
        out[(row_off + row0 + r) * 2 + 0] = p0 + bfc[0];
        out[(row_off + row0 + r) * 2 + 1] = p1 + bfc[1];
    }
}

extern "C" void kernel_launch(void* const* d_in, const int* in_sizes, int n_in,
                              void* d_out, int out_size, void* d_ws, size_t ws_size,
                              hipStream_t stream) {
    const float* x   = (const float*)d_in[0];
    const float* Win = (const float*)d_in[1];
    const float* bin = (const float*)d_in[2];
    const float* Wh  = (const float*)d_in[3];
    const float* bh  = (const float*)d_in[4];
    const float* Wfc = (const float*)d_in[5];
    const float* bfc = (const float*)d_in[6];
    float* out = (float*)d_out;

    const size_t need_full = (size_t)B_TOT * L_SEQ * G_DIM * sizeof(unsigned short); // 157.3 MB
    unsigned short* tiw = (unsigned short*)d_ws;

    if (ws_size >= need_full) {
        ti_proj_kernel<<<dim3(B_TOT * L_SEQ / 16), dim3(256), 0, stream>>>(x, Win, tiw);
        gru_rec_kernel<0><<<dim3(B_TOT / ROWS), dim3(256), 0, stream>>>(
            x, tiw, Win, bin, Wh, bh, Wfc, bfc, out, 0);
    } else if (ws_size >= need_full / 2) {
        for (int c = 0; c < 2; ++c) {
            int r0 = c * (B_TOT / 2);
            ti_proj_kernel<<<dim3((B_TOT / 2) * L_SEQ / 16), dim3(256), 0, stream>>>(
                x + (size_t)r0 * L_SEQ * E_DIM, Win, tiw);
            gru_rec_kernel<0><<<dim3((B_TOT / 2) / ROWS), dim3(256), 0, stream>>>(
                x, tiw, Win, bin, Wh, bh, Wfc, bfc, out, r0);
        }
    } else {
        gru_rec_kernel<1><<<dim3(B_TOT / ROWS), dim3(256), 0, stream>>>(
            x, tiw, Win, bin, Wh, bh, Wfc, bfc, out, 0);
    }
}